// Round 8
// baseline (432.919 us; speedup 1.0000x reference)
//
#include <hip/hip_runtime.h>
#include <hip/hip_bf16.h>
#include <math.h>

// LSMDecoder: out = sigmoid(bias - wg*N*dist_gam - wd*N*dist_del), plus zd/gd_raw/dd_raw.
// x[i,j] = cvec_i - bco_j - N * dot(A_i, B_j), 512-dim fp16 stacks, fp32 MFMA accumulate.
// Diagonal overridden exactly. R8: pair K-loop double-buffered, ONE barrier per kt
// (prefetch kt+1 under kt's MFMA; barrier count 16->8; loads get a full consume-phase
// to land before the vmcnt drain). LDS 64 KB, 2 blocks/CU.

#define NSZ 8192
#define DLAT 128

typedef _Float16 half8 __attribute__((ext_vector_type(8)));
typedef float f32x4 __attribute__((ext_vector_type(4)));
typedef float f32x16 __attribute__((ext_vector_type(16)));

__device__ __forceinline__ void gl_lds16(const void* g, void* l) {
    __builtin_amdgcn_global_load_lds(
        (const __attribute__((address_space(1))) void*)g,
        (__attribute__((address_space(3))) void*)l, 16, 0, 0);
}

__device__ __forceinline__ float fast_sigmoid(float x) {
    float e = __builtin_amdgcn_exp2f(-1.44269504f * x);
    return __builtin_amdgcn_rcpf(1.0f + e);
}

// ---------------- P1: column softmax of Wz/Wg/Wd -> transposed fp16 tables ------------------
__global__ void softmax_cols(const float* __restrict__ Wz, const float* __restrict__ Wg,
                             const float* __restrict__ Wd, _Float16* __restrict__ Tt) {
    int col = blockIdx.x & 127;
    int m = blockIdx.x >> 7;
    const float* W = (m == 0) ? Wz : (m == 1 ? Wg : Wd);
    _Float16* To = Tt + (size_t)m * 65536 + (size_t)col * 512;
    int l = threadIdx.x;  // 64 threads = 1 wave
    float v[8];
    float mx = -3.4e38f;
    for (int i = 0; i < 8; ++i) {
        v[i] = W[(size_t)(i * 64 + l) * 128 + col];
        mx = fmaxf(mx, v[i]);
    }
    for (int off = 32; off; off >>= 1) mx = fmaxf(mx, __shfl_xor(mx, off));
    float s = 0.f;
    for (int i = 0; i < 8; ++i) { v[i] = expf(v[i] - mx); s += v[i]; }
    for (int off = 32; off; off >>= 1) s += __shfl_xor(s, off);
    float inv = 1.0f / s;
    for (int i = 0; i < 8; ++i) To[i * 64 + l] = (_Float16)(v[i] * inv);
}

// ---------------- P2: fp16 MFMA GEMM  [8192x512] @ [512x128] for zd / gd_raw / dd_raw ------
__global__ __launch_bounds__(128) void gemm3_mfma(const float* __restrict__ z,
                                                  const float* __restrict__ gamma,
                                                  const float* __restrict__ delta,
                                                  const _Float16* __restrict__ Tt,
                                                  float* __restrict__ outTail) {
    int m = blockIdx.y;
    const float* A = (m == 0) ? z : (m == 1 ? gamma : delta);
    const _Float16* B = Tt + (size_t)m * 65536;
    float* C = outTail + (size_t)m * (NSZ * DLAT);
    int rowBase = blockIdx.x * 32;
    __shared__ _Float16 As[32 * 520];   // row stride 520 halves (1040 B), 33.3 KB
    int t = threadIdx.x;
    for (int s = 0; s < 16; ++s) {      // stage+convert: 32 rows x 512 k
        int id = s * 128 + t;
        int row = id >> 6, c8 = id & 63;
        const float4* src = (const float4*)(A + (size_t)(rowBase + row) * 512 + c8 * 8);
        float4 f0 = src[0], f1 = src[1];
        half8 h = {(_Float16)f0.x, (_Float16)f0.y, (_Float16)f0.z, (_Float16)f0.w,
                   (_Float16)f1.x, (_Float16)f1.y, (_Float16)f1.z, (_Float16)f1.w};
        *(half8*)(&As[row * 520 + c8 * 8]) = h;
    }
    __syncthreads();

    int l = t & 63, w = t >> 6;
    int lc = l & 15, lq = l >> 4;
    int m0 = w * 16;                    // wave's 16 rows within tile
    f32x4 acc[8] = {};
    for (int kt = 0; kt < 16; ++kt) {
        int k0 = kt * 32;
        half8 af = *(const half8*)(&As[(m0 + lc) * 520 + k0 + lq * 8]);
        for (int ni = 0; ni < 8; ++ni) {
            half8 bf = *(const half8*)(B + (size_t)(ni * 16 + lc) * 512 + k0 + lq * 8);
            acc[ni] = __builtin_amdgcn_mfma_f32_16x16x32_f16(af, bf, acc[ni], 0, 0, 0);
        }
    }
    for (int ni = 0; ni < 8; ++ni) {
        for (int r = 0; r < 4; ++r) {
            int row = rowBase + m0 + lq * 4 + r;   // C/D: row = quad*4+reg
            int col = ni * 16 + lc;                // C/D: col = lane&15
            C[(size_t)row * 128 + col] = acc[ni][r];
        }
    }
}

// ---------------- P2b: build fp16 stacked A/B [8192x512] + per-row scalars ------------------
__global__ void build_stacks(const float* __restrict__ zd, const float* __restrict__ gdr,
                             const float* __restrict__ ddr, _Float16* __restrict__ Afp,
                             _Float16* __restrict__ Bfp, float* __restrict__ cvec,
                             float* __restrict__ bco, const float* __restrict__ pb,
                             const float* __restrict__ pwg, const float* __restrict__ pwd) {
    int i = blockIdx.x;    // 8192 rows
    int k = threadIdx.x;   // 128
    float zv = zd[(size_t)i * 128 + k];
    float g = gdr[(size_t)i * 128 + k] + 1e-16f;
    float d = ddr[(size_t)i * 128 + k] + 1e-16f;
    float z2 = zv * zv;
    float u = 1.0f / g, p = 1.0f / d;
    float wg = *pwg, wd = *pwd, bias = *pb;
    _Float16* Ar = Afp + (size_t)i * 512;
    _Float16* Br = Bfp + (size_t)i * 512;
    Ar[k]       = (_Float16)(wg * u);
    Ar[128 + k] = (_Float16)(wg * zv * u);
    Ar[256 + k] = (_Float16)(wd * z2);
    Ar[384 + k] = (_Float16)(wd * zv);
    Br[k]       = (_Float16)(z2);
    Br[128 + k] = (_Float16)(-2.0f * zv);
    Br[256 + k] = (_Float16)(p);
    Br[384 + k] = (_Float16)(-2.0f * zv * p);
    float a = z2 * u, b = z2 * p;
    for (int off = 32; off; off >>= 1) { a += __shfl_down(a, off); b += __shfl_down(b, off); }
    __shared__ float sa[2], sb[2];
    if ((k & 63) == 0) { sa[k >> 6] = a; sb[k >> 6] = b; }
    __syncthreads();
    if (k == 0) {
        cvec[i] = bias - 8192.0f * wg * (sa[0] + sa[1]);
        bco[i] = 8192.0f * wd * (sb[0] + sb[1]);
    }
}

// ---------------- P3: fp16 MFMA pair kernel, 128x128 tile, K=512, 32x32x16, dbuf ------------
// LDS per buffer: 128 rows x 8 chunks of 16B, slot(r,q) = r*8 + (q ^ (r&7)).
// One barrier per kt: barrier publishes buf[kt], prefetch kt+1 issues under kt's MFMA.
// A/B operand 32x32x16: row/col = lane&31, k = (lane>>5)*8 + j.
// C/D 32x32 (m74/m101): col = lane&31, row = (reg&3) + 8*(reg>>2) + 4*(lane>>5).
__global__ __launch_bounds__(256, 2) void pair_kernel(const _Float16* __restrict__ Afp,
                                                      const _Float16* __restrict__ Bfp,
                                                      const float* __restrict__ cvec,
                                                      const float* __restrict__ bco,
                                                      const float* __restrict__ pbias,
                                                      float* __restrict__ out) {
    int bid = blockIdx.x;
    int super = bid >> 6, within = bid & 63;
    int sy = super >> 3, sx = super & 7;
    int by = sy * 8 + (within >> 3), bx = sx * 8 + (within & 7);
    int iBase = by * 128, jBase = bx * 128;

    __shared__ _Float16 As[2][128 * 64];  // 2 x 16 KB, XOR-swizzled chunks
    __shared__ _Float16 Bs[2][128 * 64];
    int t = threadIdx.x;
    int l = t & 63, w = t >> 6;
    int wm = (w >> 1) * 64, wn = (w & 1) * 64;
    int ln = l & 31, lh = l >> 5;
    f32x16 acc[2][2] = {};

    int srow = l >> 3;                 // 0..7 row within the 8-row group
    int sq = (l & 7) ^ srow;           // permuted chunk index within the row
    // wave-invariant staging bases
    const _Float16* gA0 = Afp + (size_t)iBase * 512 + sq * 8;
    const _Float16* gB0 = Bfp + (size_t)jBase * 512 + sq * 8;

    // hoisted epilogue scalars (latency hidden under K-loop)
    float bias = *pbias;
    float bjv[2];
    for (int n2 = 0; n2 < 2; ++n2) bjv[n2] = bco[jBase + wn + n2 * 32 + ln];
    float civ[2][16];
    for (int m2 = 0; m2 < 2; ++m2)
        for (int reg = 0; reg < 16; ++reg)
            civ[m2][reg] = cvec[iBase + wm + m2 * 32 + (reg & 3) + 8 * (reg >> 2) + 4 * lh];

    // prefetch kt=0 into buffer 0
    for (int s = 0; s < 4; ++s) {
        int rr = (w * 4 + s) * 8 + srow;
        gl_lds16(gA0 + (size_t)rr * 512, &As[0][(w * 4 + s) * 512]);
        gl_lds16(gB0 + (size_t)rr * 512, &Bs[0][(w * 4 + s) * 512]);
    }

    for (int kt = 0; kt < 8; ++kt) {
        int cur = kt & 1;
        __syncthreads();               // publishes buf[cur]; drains in-flight prefetch
        if (kt < 7) {                  // prefetch kt+1 under this kt's compute
            int k1 = (kt + 1) * 64;
            for (int s = 0; s < 4; ++s) {
                int rr = (w * 4 + s) * 8 + srow;
                gl_lds16(gA0 + (size_t)rr * 512 + k1, &As[cur ^ 1][(w * 4 + s) * 512]);
                gl_lds16(gB0 + (size_t)rr * 512 + k1, &Bs[cur ^ 1][(w * 4 + s) * 512]);
            }
        }
        for (int ks = 0; ks < 4; ++ks) {   // K=16 per step
            int q = ks * 2 + lh;           // 16B chunk index within the 64-k stage
            half8 af[2], bf[2];
            for (int m2 = 0; m2 < 2; ++m2) {
                int r = wm + m2 * 32 + ln;
                af[m2] = *(const half8*)(&As[cur][((r << 3) + (q ^ (r & 7))) << 3]);
            }
            for (int n2 = 0; n2 < 2; ++n2) {
                int r = wn + n2 * 32 + ln;
                bf[n2] = *(const half8*)(&Bs[cur][((r << 3) + (q ^ (r & 7))) << 3]);
            }
            for (int m2 = 0; m2 < 2; ++m2)
                for (int n2 = 0; n2 < 2; ++n2)
                    acc[m2][n2] = __builtin_amdgcn_mfma_f32_32x32x16_f16(af[m2], bf[n2],
                                                                         acc[m2][n2], 0, 0, 0);
        }
    }

    bool diagBlock = (iBase == jBase);
    for (int m2 = 0; m2 < 2; ++m2) {
        for (int n2 = 0; n2 < 2; ++n2) {
            int j = jBase + wn + n2 * 32 + ln;
            for (int reg = 0; reg < 16; ++reg) {
                int i = iBase + wm + m2 * 32 + (reg & 3) + 8 * (reg >> 2) + 4 * lh;
                float x = civ[m2][reg] - bjv[n2] - 8192.0f * acc[m2][n2][reg];
                if (diagBlock) { if (i == j) x = bias; }     // uniform outer branch
                out[(size_t)i * NSZ + j] = fast_sigmoid(x);
            }
        }
    }
}

extern "C" void kernel_launch(void* const* d_in, const int* in_sizes, int n_in,
                              void* d_out, int out_size, void* d_ws, size_t ws_size,
                              hipStream_t stream) {
    const float* z = (const float*)d_in[0];
    const float* gamma = (const float*)d_in[1];
    const float* delta = (const float*)d_in[2];
    const float* Wz = (const float*)d_in[3];
    const float* Wg = (const float*)d_in[4];
    const float* Wd = (const float*)d_in[5];
    const float* pb = (const float*)d_in[6];
    const float* pwg = (const float*)d_in[7];
    const float* pwd = (const float*)d_in[8];

    float* out = (float*)d_out;
    float* zd_out = out + (size_t)NSZ * NSZ;
    float* gd_out = zd_out + (size_t)NSZ * DLAT;
    float* dd_out = gd_out + (size_t)NSZ * DLAT;

    float* wsf = (float*)d_ws;
    _Float16* Tt = (_Float16*)wsf;        // 3*512*128 fp16 = 384 KB (transposed tables)
    float* cvec = wsf + 98304;
    float* bco = cvec + 8192;
    _Float16* Afp = (_Float16*)(bco + 8192);          // 16B aligned; 8 MB
    _Float16* Bfp = Afp + (size_t)NSZ * 512;          // 8 MB

    softmax_cols<<<384, 64, 0, stream>>>(Wz, Wg, Wd, Tt);
    gemm3_mfma<<<dim3(256, 3), 128, 0, stream>>>(z, gamma, delta, Tt, zd_out);
    build_stacks<<<NSZ, 128, 0, stream>>>(zd_out, gd_out, dd_out, Afp, Bfp, cvec, bco,
                                          pb, pwg, pwd);
    pair_kernel<<<4096, 256, 0, stream>>>(Afp, Bfp, cvec, bco, pb, out);
}